// Round 4
// baseline (128.989 us; speedup 1.0000x reference)
//
#include <hip/hip_runtime.h>

#define TPB 256
#define R 8           // source points per lane
#define CHUNKS 64     // CH = n/CHUNKS = 256 targets per block (== TPB)
// n=16384: SB = n/(TPB*R) = 8 source-blocks/dir; grid = 2*SB*CHUNKS = 1024 blocks

// One fused kernel: in-block prep, min-pass, counter-gated finalize.
// min_t(|s-t|^2) = |s|^2 + min_t(|t|^2 - 2 s.t)
__global__ __launch_bounds__(TPB) void chamfer_kernel(
        const float* __restrict__ A, const float* __restrict__ B,
        unsigned* __restrict__ pmins, int* __restrict__ cnt,
        float* __restrict__ out, int n, int nblocks) {
    const int SB = n / (TPB * R);
    const int CH = n / CHUNKS;   // 256
    int b = blockIdx.x;
    int dir = b / (SB * CHUNKS);
    int rem = b % (SB * CHUNKS);
    int chunk = rem / SB;
    int sblk = rem % SB;
    const float* __restrict__ src = dir ? B : A;
    const float* __restrict__ tgt = dir ? A : B;

    // --- target tile: raw loads + |t|^2, packed into LDS ---
    __shared__ float4 tile[256];
    for (int i = threadIdx.x; i < CH; i += TPB) {
        int t = chunk * CH + i;
        float x = tgt[3 * t], y = tgt[3 * t + 1], z = tgt[3 * t + 2];
        tile[i] = make_float4(x, y, z, x * x + y * y + z * z);
    }

    // --- source prologue: raw loads, fold -2x into registers ---
    float ax[R], ay[R], az[R], sw[R], m[R];
    int s0 = sblk * TPB * R + threadIdx.x;
#pragma unroll
    for (int r = 0; r < R; ++r) {
        int si = s0 + r * TPB;
        float x = src[3 * si], y = src[3 * si + 1], z = src[3 * si + 2];
        ax[r] = -2.0f * x; ay[r] = -2.0f * y; az[r] = -2.0f * z;
        sw[r] = x * x + y * y + z * z;
        m[r] = __builtin_inff();
    }
    __syncthreads();

    // --- min loop with distance-1 register prefetch of the broadcast read ---
    float4 p = tile[0];
#pragma unroll 8
    for (int j = 0; j < CH; ++j) {
        float4 pn = tile[(j + 1) & (CH - 1)];  // prefetch next (wraps harmlessly)
#pragma unroll
        for (int r = 0; r < R; ++r) {
            float d = fmaf(ax[r], p.x, fmaf(ay[r], p.y, fmaf(az[r], p.z, p.w)));
            m[r] = fminf(m[r], d);
        }
        p = pn;
    }

    // positive floats are monotone under unsigned compare -> uint atomicMin
#pragma unroll
    for (int r = 0; r < R; ++r)
        atomicMin(&pmins[dir * n + s0 + r * TPB], __float_as_uint(m[r] + sw[r]));

    // --- counter-gated finalize: last block sums all 2n mins ---
    __shared__ int last;
    if (threadIdx.x == 0) {
        __threadfence();                      // release our atomicMins
        int old = atomicAdd(cnt, 1);          // cnt init = -1 (0xFF memset)
        last = (old == nblocks - 2) ? 1 : 0;
    }
    __syncthreads();
    if (last) {
        __threadfence();                      // acquire all blocks' mins
        float sum = 0.0f;
        for (int i = threadIdx.x; i < 2 * n; i += TPB) {
            unsigned u = __hip_atomic_load(&pmins[i], __ATOMIC_RELAXED,
                                           __HIP_MEMORY_SCOPE_AGENT);
            sum += __uint_as_float(u);
        }
        for (int off = 32; off > 0; off >>= 1)
            sum += __shfl_down(sum, off, 64);
        __shared__ float wsum[TPB / 64];
        int lane = threadIdx.x & 63, wid = threadIdx.x >> 6;
        if (lane == 0) wsum[wid] = sum;
        __syncthreads();
        if (threadIdx.x == 0) {
            float t = 0.0f;
            for (int w = 0; w < TPB / 64; ++w) t += wsum[w];
            out[0] = t / (float)(2 * n);
        }
    }
}

extern "C" void kernel_launch(void* const* d_in, const int* in_sizes, int n_in,
                              void* d_out, int out_size, void* d_ws, size_t ws_size,
                              hipStream_t stream) {
    const float* a = (const float*)d_in[0];
    const float* b = (const float*)d_in[1];
    int n = in_sizes[0] / 3;  // 16384
    float* out = (float*)d_out;
    char* ws = (char*)d_ws;
    unsigned* pmins = (unsigned*)ws;              // 2n uints = 128 KB
    int* cnt = (int*)(ws + 2 * (size_t)n * 4);    // 1 int, init -1

    // single memset: pmins = 0xFFFFFFFF (umax), cnt = -1
    hipMemsetAsync(ws, 0xFF, 2 * (size_t)n * 4 + 64, stream);
    int SB = n / (TPB * R);
    int nblocks = 2 * SB * CHUNKS;  // 1024
    chamfer_kernel<<<nblocks, TPB, 0, stream>>>(a, b, pmins, cnt, out, n, nblocks);
}

// Round 5
// 115.735 us; speedup vs baseline: 1.1145x; 1.1145x over previous
//
#include <hip/hip_runtime.h>

#define TPB 256
#define R 8           // source points per lane
#define CHUNKS 64     // CH = n/CHUNKS = 256 targets per block
// n=16384: SB = n/(TPB*R) = 8 source-blocks/dir; grid = 2*SB*CHUNKS = 1024 blocks

// Pack {x,y,z,|p|^2}; init pmins = 0xFFFFFFFF (uint +inf-max), acc/cnt = 0.
__global__ __launch_bounds__(TPB) void prep_kernel(
        const float* __restrict__ a, const float* __restrict__ b,
        float4* __restrict__ pa, float4* __restrict__ pb,
        unsigned* __restrict__ pmins, float* __restrict__ acc,
        unsigned* __restrict__ cnt, int n) {
    int idx = blockIdx.x * blockDim.x + threadIdx.x;
    if (idx < n) {
        float x = a[3 * idx], y = a[3 * idx + 1], z = a[3 * idx + 2];
        pa[idx] = make_float4(x, y, z, x * x + y * y + z * z);
    } else if (idx < 2 * n) {
        int i = idx - n;
        float x = b[3 * i], y = b[3 * i + 1], z = b[3 * i + 2];
        pb[i] = make_float4(x, y, z, x * x + y * y + z * z);
    }
    if (idx < 2 * n) pmins[idx] = 0xFFFFFFFFu;
    if (idx == 0) { acc[0] = 0.0f; cnt[0] = 0u; }
}

// min_t(|s-t|^2) = |s|^2 + min_t(|t|^2 - 2 s.t)
// Targets are wave-uniform -> compiler emits s_load_dwordx4 on the scalar
// pipe; the VALU stream is pure fma+min (1 SGPR operand per inst, legal).
__global__ __launch_bounds__(TPB) void minpass_kernel(
        const float4* __restrict__ pa, const float4* __restrict__ pb,
        unsigned* __restrict__ pmins, int n) {
    const int SB = n / (TPB * R);
    const int CH = n / CHUNKS;   // 256
    int b = blockIdx.x;
    int dir = b / (SB * CHUNKS);
    int rem = b % (SB * CHUNKS);
    int chunk = rem / SB;
    int sblk = rem % SB;
    const float4* __restrict__ src = dir ? pb : pa;
    const float4* __restrict__ tgt = dir ? pa : pb;

    float ax[R], ay[R], az[R], sw[R], m[R];
    int s0 = sblk * TPB * R + threadIdx.x;  // stride-TPB between r's: coalesced
#pragma unroll
    for (int r = 0; r < R; ++r) {
        float4 s = src[s0 + r * TPB];
        ax[r] = -2.0f * s.x; ay[r] = -2.0f * s.y; az[r] = -2.0f * s.z;
        sw[r] = s.w; m[r] = __builtin_inff();
    }

    int base = chunk * CH;
#pragma unroll 8
    for (int j = 0; j < CH; ++j) {
        float4 p = tgt[base + j];  // uniform address -> scalar load
#pragma unroll
        for (int r = 0; r < R; ++r) {
            float d = fmaf(ax[r], p.x, fmaf(ay[r], p.y, fmaf(az[r], p.z, p.w)));
            m[r] = fminf(m[r], d);
        }
    }

    // nonneg floats are monotone under unsigned compare -> uint atomicMin
#pragma unroll
    for (int r = 0; r < R; ++r)
        atomicMin(&pmins[dir * n + s0 + r * TPB], __float_as_uint(m[r] + sw[r]));
}

// 32 blocks x 256 threads: each thread sums one uint4; atomicAdd + gated out.
__global__ __launch_bounds__(TPB) void finalize_kernel(
        const uint4* __restrict__ pmins, float* __restrict__ acc,
        unsigned* __restrict__ cnt, float* __restrict__ out, int n, int nblocks) {
    int i = blockIdx.x * TPB + threadIdx.x;  // i-th uint4, total 2n/4
    uint4 v = pmins[i];
    float sum = __uint_as_float(v.x) + __uint_as_float(v.y)
              + __uint_as_float(v.z) + __uint_as_float(v.w);
    for (int off = 32; off > 0; off >>= 1)
        sum += __shfl_down(sum, off, 64);
    __shared__ float wsum[TPB / 64];
    int lane = threadIdx.x & 63, wid = threadIdx.x >> 6;
    if (lane == 0) wsum[wid] = sum;
    __syncthreads();
    if (threadIdx.x == 0) {
        float t = 0.0f;
        for (int w = 0; w < TPB / 64; ++w) t += wsum[w];
        atomicAdd(acc, t);
        __threadfence();
        unsigned old = atomicAdd(cnt, 1u);
        if (old == (unsigned)(nblocks - 1)) {
            float a0 = atomicAdd(acc, 0.0f);  // device-scope coherent read
            out[0] = a0 / (float)(2 * n);
        }
    }
}

extern "C" void kernel_launch(void* const* d_in, const int* in_sizes, int n_in,
                              void* d_out, int out_size, void* d_ws, size_t ws_size,
                              hipStream_t stream) {
    const float* a = (const float*)d_in[0];
    const float* b = (const float*)d_in[1];
    int n = in_sizes[0] / 3;  // 16384
    float* out = (float*)d_out;
    char* ws = (char*)d_ws;
    float* acc = (float*)ws;                 // 1 float
    unsigned* cnt = (unsigned*)(ws + 8);     // 1 uint
    float4* pa = (float4*)(ws + 256);
    float4* pb = pa + n;
    unsigned* pmins = (unsigned*)(ws + 256 + 2 * (size_t)n * sizeof(float4));

    prep_kernel<<<(2 * n + TPB - 1) / TPB, TPB, 0, stream>>>(
        a, b, pa, pb, pmins, acc, cnt, n);
    int SB = n / (TPB * R);
    minpass_kernel<<<2 * SB * CHUNKS, TPB, 0, stream>>>(pa, pb, pmins, n);
    int fblocks = (2 * n / 4) / TPB;  // 32
    finalize_kernel<<<fblocks, TPB, 0, stream>>>(
        (const uint4*)pmins, acc, cnt, out, n, fblocks);
}

// Round 6
// 99.085 us; speedup vs baseline: 1.3018x; 1.1680x over previous
//
#include <hip/hip_runtime.h>

#define TPB 256
#define R 8           // source points per lane
#define CHUNKS 64     // CH = n/CHUNKS = 256 targets per block
// n=16384: SB = n/(TPB*R) = 8 source-blocks/dir; grid = 2*SB*CHUNKS = 1024 blocks
// __launch_bounds__(256,4): 4 waves/EU = 16 waves/CU = 4 blocks/CU, VGPR cap 128
// (default budget forced VGPR<=40 and fissioned the r-loop -> extra ds_reads)

// Pack {x,y,z,|p|^2}; init pmins = 0xFFFFFFFF (uint-max), acc/cnt = 0.
__global__ __launch_bounds__(TPB) void prep_kernel(
        const float* __restrict__ a, const float* __restrict__ b,
        float4* __restrict__ pa, float4* __restrict__ pb,
        unsigned* __restrict__ pmins, float* __restrict__ acc,
        unsigned* __restrict__ cnt, int n) {
    int idx = blockIdx.x * blockDim.x + threadIdx.x;
    if (idx < n) {
        float x = a[3 * idx], y = a[3 * idx + 1], z = a[3 * idx + 2];
        pa[idx] = make_float4(x, y, z, x * x + y * y + z * z);
    } else if (idx < 2 * n) {
        int i = idx - n;
        float x = b[3 * i], y = b[3 * i + 1], z = b[3 * i + 2];
        pb[i] = make_float4(x, y, z, x * x + y * y + z * z);
    }
    if (idx < 2 * n) pmins[idx] = 0xFFFFFFFFu;
    if (idx == 0) { acc[0] = 0.0f; cnt[0] = 0u; }
}

// min_t(|s-t|^2) = |s|^2 + min_t(|t|^2 - 2 s.t)
__global__ __launch_bounds__(TPB, 4) void minpass_kernel(
        const float4* __restrict__ pa, const float4* __restrict__ pb,
        unsigned* __restrict__ pmins, int n) {
    const int SB = n / (TPB * R);
    const int CH = n / CHUNKS;   // 256
    int b = blockIdx.x;
    int dir = b / (SB * CHUNKS);
    int rem = b % (SB * CHUNKS);
    int chunk = rem / SB;
    int sblk = rem % SB;
    const float4* __restrict__ src = dir ? pb : pa;
    const float4* __restrict__ tgt = dir ? pa : pb;

    __shared__ float4 tile[256];  // CH == 256
    int base = chunk * CH;
    for (int i = threadIdx.x; i < CH; i += TPB)
        tile[i] = tgt[base + i];

    float ax[R], ay[R], az[R], sw[R], m[R];
    int s0 = sblk * TPB * R + threadIdx.x;  // stride-TPB between r's: coalesced
#pragma unroll
    for (int r = 0; r < R; ++r) {
        float4 s = src[s0 + r * TPB];
        ax[r] = -2.0f * s.x; ay[r] = -2.0f * s.y; az[r] = -2.0f * s.z;
        sw[r] = s.w; m[r] = __builtin_inff();
    }
    __syncthreads();

    // 2 targets/iter: 6 v_fma + 1 v_min3 per lane per 2 pairs
#pragma unroll 4
    for (int j = 0; j < CH; j += 2) {
        float4 p0 = tile[j];
        float4 p1 = tile[j + 1];
#pragma unroll
        for (int r = 0; r < R; ++r) {
            float d0 = fmaf(ax[r], p0.x, fmaf(ay[r], p0.y, fmaf(az[r], p0.z, p0.w)));
            float d1 = fmaf(ax[r], p1.x, fmaf(ay[r], p1.y, fmaf(az[r], p1.z, p1.w)));
            m[r] = fminf(m[r], fminf(d0, d1));  // -> v_min3_f32
        }
    }

    // nonneg floats monotone under unsigned compare -> uint atomicMin
#pragma unroll
    for (int r = 0; r < R; ++r)
        atomicMin(&pmins[dir * n + s0 + r * TPB], __float_as_uint(m[r] + sw[r]));
}

// 32 blocks x 256 threads: each thread sums one uint4; atomicAdd + gated out.
__global__ __launch_bounds__(TPB) void finalize_kernel(
        const uint4* __restrict__ pmins, float* __restrict__ acc,
        unsigned* __restrict__ cnt, float* __restrict__ out, int n, int nblocks) {
    int i = blockIdx.x * TPB + threadIdx.x;  // i-th uint4, total 2n/4
    uint4 v = pmins[i];
    float sum = __uint_as_float(v.x) + __uint_as_float(v.y)
              + __uint_as_float(v.z) + __uint_as_float(v.w);
    for (int off = 32; off > 0; off >>= 1)
        sum += __shfl_down(sum, off, 64);
    __shared__ float wsum[TPB / 64];
    int lane = threadIdx.x & 63, wid = threadIdx.x >> 6;
    if (lane == 0) wsum[wid] = sum;
    __syncthreads();
    if (threadIdx.x == 0) {
        float t = 0.0f;
        for (int w = 0; w < TPB / 64; ++w) t += wsum[w];
        atomicAdd(acc, t);
        __threadfence();
        unsigned old = atomicAdd(cnt, 1u);
        if (old == (unsigned)(nblocks - 1)) {
            float a0 = atomicAdd(acc, 0.0f);  // device-scope coherent read
            out[0] = a0 / (float)(2 * n);
        }
    }
}

extern "C" void kernel_launch(void* const* d_in, const int* in_sizes, int n_in,
                              void* d_out, int out_size, void* d_ws, size_t ws_size,
                              hipStream_t stream) {
    const float* a = (const float*)d_in[0];
    const float* b = (const float*)d_in[1];
    int n = in_sizes[0] / 3;  // 16384
    float* out = (float*)d_out;
    char* ws = (char*)d_ws;
    float* acc = (float*)ws;                 // 1 float
    unsigned* cnt = (unsigned*)(ws + 8);     // 1 uint
    float4* pa = (float4*)(ws + 256);
    float4* pb = pa + n;
    unsigned* pmins = (unsigned*)(ws + 256 + 2 * (size_t)n * sizeof(float4));

    prep_kernel<<<(2 * n + TPB - 1) / TPB, TPB, 0, stream>>>(
        a, b, pa, pb, pmins, acc, cnt, n);
    int SB = n / (TPB * R);
    minpass_kernel<<<2 * SB * CHUNKS, TPB, 0, stream>>>(pa, pb, pmins, n);
    int fblocks = (2 * n / 4) / TPB;  // 32
    finalize_kernel<<<fblocks, TPB, 0, stream>>>(
        (const uint4*)pmins, acc, cnt, out, n, fblocks);
}